// Round 1
// baseline (1283.506 us; speedup 1.0000x reference)
//
#include <hip/hip_runtime.h>

// GaussianSamplingPredict: B=1024, C=100, S=1000
//   scaled_cov = cov + 1e-6 I  (DECODING_TIME = 1.0)
//   L = cholesky(scaled_cov)                    [B,C,C]
//   t[b,s,d] = u[b,d] + sum_c z[s,c] * L[b,d,c]
//   out[b,d] = mean_s softmax_d(t[b,s,:])[d]
//
// One block per batch b. Fully fused: Cholesky in LDS -> repack -> fp32
// register-tiled matmul + online softmax + mean. samples tensor (410 MB)
// never hits HBM.

#define CC   100
#define SS   1000
#define PCH  101     // Cholesky-phase LDS stride (odd -> conflict-free rows)
#define PMM  104     // matmul-phase stride (mult of 4 -> 16B-aligned float4)
#define EPSF 1e-6f

__global__ __launch_bounds__(256, 2)
void gsp_kernel(const float* __restrict__ u,
                const float* __restrict__ cov,
                const float* __restrict__ z,
                float* __restrict__ out, int B) {
    // 100*104*4 = 41.6 KB main buffer (Cholesky uses first 100*101 floats)
    __shared__ alignas(16) float LS[CC * PMM];
    __shared__ float ush[CC];
    __shared__ float outWv[4 * CC];

    const int tid = threadIdx.x;
    const int b   = blockIdx.x;

    // ---- Phase A: load cov into transposed storage M[x][y] = A[y][x] ----
    // cov is symmetric, so M[r][c] = cov[r][c] works directly.
    for (int idx = tid; idx < CC * CC; idx += 256) {
        const int r = idx / CC;
        const int c = idx - r * CC;
        float v = cov[(size_t)b * (CC * CC) + idx];
        if (r == c) v += EPSF;
        LS[r * PCH + c] = v;
    }
    if (tid < CC) ush[tid] = u[(size_t)b * CC + tid];
    __syncthreads();

    // ---- Phase B: Cholesky, transposed storage: LS[x*PCH+y] = L[y][x], y>=x ----
    {
        const int tx = tid & 63;
        const int ty = tid >> 6;
        for (int j = 0; j < CC; ++j) {
            if (tid == 0) LS[j * PCH + j] = sqrtf(LS[j * PCH + j]);
            __syncthreads();
            const float dinv = 1.0f / LS[j * PCH + j];
            for (int i = j + 1 + tid; i < CC; i += 256)
                LS[j * PCH + i] *= dinv;          // row access: conflict-free
            __syncthreads();
            // rank-1 trailing update: M[k][i] -= M[j][i]*M[j][k], j<k<=i
            for (int k = j + 1 + ty; k < CC; k += 4) {
                const float lkj = LS[j * PCH + k];      // broadcast
                for (int i = k + tx; i < CC; i += 64)
                    LS[k * PCH + i] -= LS[j * PCH + i] * lkj;  // row access
            }
            __syncthreads();
        }
    }

    // ---- Phase C: repack to row-major L[d][c] (stride PMM), zero c>d ----
    {
        float tmp[41];
        #pragma unroll
        for (int t = 0; t < 41; ++t) {
            const int idx = tid + t * 256;
            float v = 0.0f;
            if (idx < CC * PMM) {
                const int d = idx / PMM;
                const int c = idx - d * PMM;
                if (c <= d) v = LS[c * PCH + d];   // M[c][d] = L[d][c]
            }
            tmp[t] = v;
        }
        __syncthreads();
        #pragma unroll
        for (int t = 0; t < 41; ++t) {
            const int idx = tid + t * 256;
            if (idx < CC * PMM) LS[idx] = tmp[t];
        }
        __syncthreads();
    }

    // ---- Phase D: matmul + softmax + mean ----
    // 4-lane group: lane q = tid&3 owns d in [25q, 25q+25); group g = tid>>2
    // owns 4 consecutive s-rows per pass. 4 passes of 256 rows cover S=1000
    // (tail masked).
    const int q = tid & 3;
    const int g = tid >> 2;
    const float4* __restrict__ z4 = reinterpret_cast<const float4*>(z);

    float regAcc[25];
    #pragma unroll
    for (int dd = 0; dd < 25; ++dd) regAcc[dd] = 0.0f;

    for (int pass = 0; pass < 4; ++pass) {
        const int s0 = pass * 256 + g * 4;
        const int r0 = (s0 + 0 < SS) ? s0 + 0 : SS - 1;
        const int r1 = (s0 + 1 < SS) ? s0 + 1 : SS - 1;
        const int r2 = (s0 + 2 < SS) ? s0 + 2 : SS - 1;
        const int r3 = (s0 + 3 < SS) ? s0 + 3 : SS - 1;

        float acc[4][25];
        #pragma unroll
        for (int r = 0; r < 4; ++r)
            #pragma unroll
            for (int dd = 0; dd < 25; ++dd) acc[r][dd] = 0.0f;

        for (int cb = 0; cb < 25; ++cb) {
            const float4 z0 = z4[r0 * 25 + cb];
            const float4 z1 = z4[r1 * 25 + cb];
            const float4 z2 = z4[r2 * 25 + cb];
            const float4 z3 = z4[r3 * 25 + cb];
            #pragma unroll
            for (int dd = 0; dd < 25; ++dd) {
                const float4 lv =
                    *reinterpret_cast<const float4*>(&LS[(q * 25 + dd) * PMM + cb * 4]);
                acc[0][dd] += z0.x * lv.x + z0.y * lv.y + z0.z * lv.z + z0.w * lv.w;
                acc[1][dd] += z1.x * lv.x + z1.y * lv.y + z1.z * lv.z + z1.w * lv.w;
                acc[2][dd] += z2.x * lv.x + z2.y * lv.y + z2.z * lv.z + z2.w * lv.w;
                acc[3][dd] += z3.x * lv.x + z3.y * lv.y + z3.z * lv.z + z3.w * lv.w;
            }
        }

        // add u
        #pragma unroll
        for (int dd = 0; dd < 25; ++dd) {
            const float uv = ush[q * 25 + dd];
            #pragma unroll
            for (int r = 0; r < 4; ++r) acc[r][dd] += uv;
        }

        // softmax per row (100 classes split across the 4-lane group) + mean acc
        #pragma unroll
        for (int r = 0; r < 4; ++r) {
            float m = acc[r][0];
            #pragma unroll
            for (int dd = 1; dd < 25; ++dd) m = fmaxf(m, acc[r][dd]);
            m = fmaxf(m, __shfl_xor(m, 1));
            m = fmaxf(m, __shfl_xor(m, 2));
            float sum = 0.0f;
            #pragma unroll
            for (int dd = 0; dd < 25; ++dd) {
                const float e = __expf(acc[r][dd] - m);
                acc[r][dd] = e;
                sum += e;
            }
            sum += __shfl_xor(sum, 1);
            sum += __shfl_xor(sum, 2);
            const float w = (s0 + r < SS) ? (1.0f / sum) : 0.0f;
            #pragma unroll
            for (int dd = 0; dd < 25; ++dd) regAcc[dd] += acc[r][dd] * w;
        }
    }

    // ---- reduce: lanes with same q within wave (xor 4,8,16,32), then waves ----
    #pragma unroll
    for (int dd = 0; dd < 25; ++dd) {
        float v = regAcc[dd];
        v += __shfl_xor(v, 4);
        v += __shfl_xor(v, 8);
        v += __shfl_xor(v, 16);
        v += __shfl_xor(v, 32);
        regAcc[dd] = v;
    }
    const int lane = tid & 63;
    const int wv   = tid >> 6;
    if (lane < 4) {
        #pragma unroll
        for (int dd = 0; dd < 25; ++dd)
            outWv[wv * CC + lane * 25 + dd] = regAcc[dd];
    }
    __syncthreads();
    for (int d = tid; d < CC; d += 256) {
        out[(size_t)b * CC + d] =
            (outWv[d] + outWv[CC + d] + outWv[2 * CC + d] + outWv[3 * CC + d]) *
            (1.0f / (float)SS);
    }
}

extern "C" void kernel_launch(void* const* d_in, const int* in_sizes, int n_in,
                              void* d_out, int out_size, void* d_ws, size_t ws_size,
                              hipStream_t stream) {
    const float* u   = (const float*)d_in[0];
    const float* cov = (const float*)d_in[1];
    const float* z   = (const float*)d_in[2];
    float* out = (float*)d_out;
    const int B = in_sizes[0] / CC;   // 1024
    gsp_kernel<<<dim3(B), dim3(256), 0, stream>>>(u, cov, z, out, B);
}